// Round 9
// baseline (254.610 us; speedup 1.0000x reference)
//
#include <hip/hip_runtime.h>

// Problem: B=2048 batches, N=64 members, D=256, H=16.
// out[b,n] = softmax_n( relu( (N*u[b,n,:] - sum_n u[b,n,:]) * item[b,:] @ W1 + b1 ) @ W2 )
// (b2 dropped: softmax is shift-invariant.)
//
// R8 lesson: splitting batches across waves doubled TLP but ALSO duplicated
// W1 LDS reads (DS ops/batch 576 -> 832), canceling the gain. W1/item/b1/W2
// are wave-uniform data and belong in SGPRs, not the DS pipe.
//
// This version: LANE = MEMBER n. One wave per batch; lane n accumulates all
// 16 h in acc[4] (16 VGPRs), iterating d serially. Per step the W1 row block
// and item float4 have wave-uniform addresses (loop counters only) -> the
// compiler emits s_load (scalar cache; W1=16KB fully resident); v_fma reads
// the SGPR operand directly. DS per wave: 576 -> 128 ops (64 swizzled
// ds_write_b128 staging + 64 ds_read_b128, both at the 8-bank-quad optimal
// floor). Epilogue: h is lane-local -> no q-replication, no h-butterflies;
// tt and softmax are plain 64-lane butterflies; store is 64 contiguous lanes.
// Block = 64 (1 wave, 1 batch, wave-private 8KB tile), grid = 2048 ->
// 16 workgroups/CU = 16 waves/CU (2x R8 TLP). Zero barriers in the kernel.

static constexpr int NMEM  = 64;
static constexpr int DDIM  = 256;
static constexpr int NTILE = 8;           // 8 d-tiles of width 32

__device__ __forceinline__ void fma4(float4& a, float s, const float4& w) {
    a.x = fmaf(s, w.x, a.x); a.y = fmaf(s, w.y, a.y);
    a.z = fmaf(s, w.z, a.z); a.w = fmaf(s, w.w, a.w);
}
__device__ __forceinline__ float4 shfl4x(const float4& v, int m) {
    float4 r;
    r.x = __shfl_xor(v.x, m, 64); r.y = __shfl_xor(v.y, m, 64);
    r.z = __shfl_xor(v.z, m, 64); r.w = __shfl_xor(v.w, m, 64);
    return r;
}
__device__ __forceinline__ void add4(float4& a, const float4& b) {
    a.x += b.x; a.y += b.y; a.z += b.z; a.w += b.w;
}

__global__ __launch_bounds__(64)
void attn_group_softmax(const float* __restrict__ u_g,     // [B,64,256]
                        const float* __restrict__ item_g,  // [B,256]
                        const float* __restrict__ W1,      // [256,16]
                        const float* __restrict__ b1,      // [16]
                        const float* __restrict__ W2,      // [16,1]
                        float* __restrict__ out)           // [B,64]
{
    __shared__ float tile[NMEM * 32];     // 8 KB, wave-private, XOR-swizzled

    const int lane = threadIdx.x;         // block = exactly 1 wave
    const int b    = blockIdx.x;          // one batch per wave
    const int row0 = lane >> 3;           // staging row 0..7 (+8i)
    const int col4 = lane & 7;            // staging float4 column (true col)
    const int sc   = col4 ^ row0;         // swizzled store slot (lane-const)
    const int rk   = lane & 7;            // read swizzle key = (n & 7)

    const float4* ug4  = (const float4*)u_g + (size_t)b * (NMEM * DDIM / 4);
    const float4* ig4  = (const float4*)(item_g + (size_t)b * DDIM); // uniform loads
    const float4* w14  = (const float4*)W1;                          // uniform loads
    float4*       t4   = (float4*)tile;
    const float4* t4c  = (const float4*)tile;

    // acc[g] = y'[n=lane][4g..4g+3], accumulated serially over all 256 d
    float4 acc[4];
    #pragma unroll
    for (int g = 0; g < 4; ++g) acc[g] = make_float4(0.f, 0.f, 0.f, 0.f);

    // prefetch tile 0 (8 x float4 per lane = full 64x32 tile)
    float4 r[8];
    #pragma unroll
    for (int i = 0; i < 8; ++i)
        r[i] = ug4[(row0 + 8 * i) * (DDIM / 4) + col4];

    for (int t = 0; t < NTILE; ++t) {
        // write tile t to LDS (XOR-swizzled slot; pure copy, item folded later)
        #pragma unroll
        for (int i = 0; i < 8; ++i)
            t4[(row0 + 8 * i) * 8 + sc] = r[i];
        // prefetch tile t+1 (overlaps compute; no barrier, wave-private tile)
        if (t + 1 < NTILE) {
            #pragma unroll
            for (int i = 0; i < 8; ++i)
                r[i] = ug4[(row0 + 8 * i) * (DDIM / 4) + (t + 1) * 8 + col4];
        }
        // compute tile t: 8 steps; per step 1 ds_read_b128 + uniform W1/item
        #pragma unroll
        for (int c = 0; c < 8; ++c) {
            const float4 uc = t4c[lane * 8 + (c ^ rk)];   // u[n][4 d's]
            const float4 it = ig4[t * 8 + c];             // uniform -> s_load
            const int rb = (t * 32 + 4 * c) * 4;          // W1 row-block base
            #pragma unroll
            for (int j = 0; j < 4; ++j) {                 // d = t*32+4c+j
                const float uj = (j == 0) ? uc.x : (j == 1) ? uc.y
                               : (j == 2) ? uc.z : uc.w;
                const float ij = (j == 0) ? it.x : (j == 1) ? it.y
                               : (j == 2) ? it.z : it.w;
                const float s = uj * ij;                  // fold item at use
                const float4 wj0 = w14[rb + 4 * j + 0];   // uniform -> s_load
                const float4 wj1 = w14[rb + 4 * j + 1];
                const float4 wj2 = w14[rb + 4 * j + 2];
                const float4 wj3 = w14[rb + 4 * j + 3];
                fma4(acc[0], s, wj0); fma4(acc[1], s, wj1);
                fma4(acc[2], s, wj2); fma4(acc[3], s, wj3);
            }
        }
        // no barrier: DS ops from one wave complete in order -> WAR-safe
    }

    // ---- tt[h] = sum over all 64 n (full-wave butterfly, 6 rounds) ----
    float4 tt0 = acc[0], tt1 = acc[1], tt2 = acc[2], tt3 = acc[3];
    #pragma unroll
    for (int m = 1; m <= 32; m <<= 1) {
        add4(tt0, shfl4x(tt0, m)); add4(tt1, shfl4x(tt1, m));
        add4(tt2, shfl4x(tt2, m)); add4(tt3, shfl4x(tt3, m));
    }

    const float4 b10 = ((const float4*)b1)[0], b11 = ((const float4*)b1)[1];
    const float4 b12 = ((const float4*)b1)[2], b13 = ((const float4*)b1)[3];
    const float4 w20 = ((const float4*)W2)[0], w21 = ((const float4*)W2)[1];
    const float4 w22 = ((const float4*)W2)[2], w23 = ((const float4*)W2)[3];

    // logit for this lane's n: sum over 16 h of relu(64*y' - tt + b1) * W2
    auto part = [](const float4& a, const float4& ttg, const float4& bg,
                   const float4& wg) -> float {
        const float zx = fmaxf(fmaf(64.f, a.x, bg.x - ttg.x), 0.f);
        const float zy = fmaxf(fmaf(64.f, a.y, bg.y - ttg.y), 0.f);
        const float zz = fmaxf(fmaf(64.f, a.z, bg.z - ttg.z), 0.f);
        const float zw = fmaxf(fmaf(64.f, a.w, bg.w - ttg.w), 0.f);
        return zx * wg.x + zy * wg.y + zz * wg.z + zw * wg.w;
    };
    const float p = part(acc[0], tt0, b10, w20) + part(acc[1], tt1, b11, w21)
                  + part(acc[2], tt2, b12, w22) + part(acc[3], tt3, b13, w23);

    // ---- softmax over the 64 lanes ----
    float mx = p;
    #pragma unroll
    for (int m = 1; m <= 32; m <<= 1) mx = fmaxf(mx, __shfl_xor(mx, m, 64));
    const float e = __expf(p - mx);
    float s = e;
    #pragma unroll
    for (int m = 1; m <= 32; m <<= 1) s += __shfl_xor(s, m, 64);

    out[(size_t)b * NMEM + lane] = e / s;   // 64 lanes, 256 B contiguous
}

extern "C" void kernel_launch(void* const* d_in, const int* in_sizes, int n_in,
                              void* d_out, int out_size, void* d_ws, size_t ws_size,
                              hipStream_t stream) {
    const float* u    = (const float*)d_in[0];  // members_embeds [2048,64,256]
    const float* item = (const float*)d_in[1];  // item_embeds   [2048,256]
    const float* W1   = (const float*)d_in[2];  // [256,16]
    const float* b1   = (const float*)d_in[3];  // [16]
    const float* W2   = (const float*)d_in[4];  // [16,1]
    // d_in[5] = b2: dropped (softmax shift-invariant)
    (void)in_sizes; (void)n_in; (void)out_size; (void)d_ws; (void)ws_size;

    attn_group_softmax<<<2048, 64, 0, stream>>>(u, item, W1, b1, W2, (float*)d_out);
}